// Round 2
// baseline (2105.922 us; speedup 1.0000x reference)
//
#include <hip/hip_runtime.h>
#include <hip/hip_bf16.h>

typedef __hip_bfloat16 bf16;

#define ROWS 53176    // B * L_TOTAL
#define LTOT 13294
#define NHEAD 8
#define DHEAD 32

__device__ __forceinline__ float ldf(const float* p) { return *p; }
__device__ __forceinline__ float ldf(const bf16* p)  { return __bfloat162float(*p); }
__device__ __forceinline__ void  stf(float* p, float v) { *p = v; }
__device__ __forceinline__ void  stf(bf16* p, float v)  { *p = __float2bfloat16(v); }

// C[M,N] = (A [+Apos]) @ W + bias  [+res] [relu]
template<typename AT, bool ADD_POS, bool RELU, bool RES, typename OT>
__global__ void gemm_kernel(const AT* __restrict__ A, const AT* __restrict__ Apos,
                            const float* __restrict__ W, const float* __restrict__ bias,
                            const float* __restrict__ res,
                            OT* __restrict__ Cout, int M, int N, int K)
{
    __shared__ float As[16][64];
    __shared__ float Bs[16][64];
    const int tid = threadIdx.x;
    const int tx = tid & 15, ty = tid >> 4;
    const int n0 = blockIdx.x * 64;
    const int m0 = blockIdx.y * 64;
    float acc[4][4] = {};
    for (int kk = 0; kk < K; kk += 16) {
#pragma unroll
        for (int i = 0; i < 4; ++i) {
            int e = tid + i * 256;
            int ml = e >> 4, kl = e & 15;
            int gm = m0 + ml;
            float va = 0.f;
            if (gm < M) {
                size_t idx = (size_t)gm * K + kk + kl;
                va = ldf(&A[idx]);
                if (ADD_POS) va += ldf(&Apos[idx]);
            }
            As[kl][ml] = va;
        }
#pragma unroll
        for (int i = 0; i < 4; ++i) {
            int e = tid + i * 256;
            int kl = e >> 6, nl = e & 63;
            Bs[kl][nl] = W[(size_t)(kk + kl) * N + n0 + nl];
        }
        __syncthreads();
#pragma unroll
        for (int k = 0; k < 16; ++k) {
            float a[4], b[4];
#pragma unroll
            for (int i = 0; i < 4; ++i) a[i] = As[k][ty * 4 + i];
#pragma unroll
            for (int j = 0; j < 4; ++j) b[j] = Bs[k][tx * 4 + j];
#pragma unroll
            for (int i = 0; i < 4; ++i)
#pragma unroll
                for (int j = 0; j < 4; ++j)
                    acc[i][j] += a[i] * b[j];
        }
        __syncthreads();
    }
#pragma unroll
    for (int i = 0; i < 4; ++i) {
        int gm = m0 + ty * 4 + i;
        if (gm >= M) continue;
#pragma unroll
        for (int j = 0; j < 4; ++j) {
            int gn = n0 + tx * 4 + j;
            float v = acc[i][j] + bias[gn];
            if (RES) v += res[(size_t)gm * N + gn];
            if (RELU) v = fmaxf(v, 0.f);
            stf(&Cout[(size_t)gm * N + gn], v);
        }
    }
}

__global__ void softmax16_kernel(float* __restrict__ aw, int n)
{
    int i = blockIdx.x * blockDim.x + threadIdx.x;
    if (i >= n) return;
    float* p = aw + (size_t)i * 16;
    float v[16];
    float m = -1e30f;
#pragma unroll
    for (int j = 0; j < 16; ++j) { v[j] = p[j]; m = fmaxf(m, v[j]); }
    float s = 0.f;
#pragma unroll
    for (int j = 0; j < 16; ++j) { v[j] = expf(v[j] - m); s += v[j]; }
    float inv = 1.f / s;
#pragma unroll
    for (int j = 0; j < 16; ++j) p[j] = v[j] * inv;
}

// one 32-lane group per (b,q,h); lane = channel d
__global__ void sample_kernel(const bf16* __restrict__ v, const float* __restrict__ off,
                              const float* __restrict__ aw, const float* __restrict__ ref,
                              bf16* __restrict__ samp)
{
    const int g = blockIdx.x * 8 + (threadIdx.x >> 5);
    const int d = threadIdx.x & 31;
    const int h = g & 7;
    const int bq = g >> 3;
    const int b = bq / LTOT;
    const float* offp = off + (size_t)bq * 256 + h * 32;
    const float* awp  = aw  + (size_t)bq * 128 + h * 16;
    const float* refp = ref + (size_t)bq * 8;
    const int HH[4] = {100, 50, 25, 13};
    const int WW[4] = {100, 50, 25, 13};
    const int SS[4] = {0, 10000, 12500, 13125};
    float acc = 0.f;
#pragma unroll
    for (int l = 0; l < 4; ++l) {
        const int H = HH[l], W = WW[l];
        const float fW = (float)W, fH = (float)H;
        const float rx = refp[l * 2 + 0];
        const float ry = refp[l * 2 + 1];
        const bf16* vb = v + (((size_t)b * LTOT + SS[l]) * NHEAD + h) * DHEAD + d;
#pragma unroll
        for (int p = 0; p < 4; ++p) {
            float ox = offp[l * 8 + p * 2 + 0];
            float oy = offp[l * 8 + p * 2 + 1];
            float wgt = awp[l * 4 + p];
            float x = (rx + ox / fW) * fW - 0.5f;
            float y = (ry + oy / fH) * fH - 0.5f;
            float x0f = floorf(x), y0f = floorf(y);
            float lx = x - x0f, ly = y - y0f;
            int x0 = (int)x0f, y0 = (int)y0f;
            float tw[4] = {(1.f - lx) * (1.f - ly), lx * (1.f - ly),
                           (1.f - lx) * ly,         lx * ly};
#pragma unroll
            for (int t = 0; t < 4; ++t) {
                int xi = x0 + (t & 1);
                int yi = y0 + (t >> 1);
                if (xi >= 0 && xi < W && yi >= 0 && yi < H) {
                    acc += wgt * tw[t] * __bfloat162float(vb[(size_t)(yi * W + xi) * (NHEAD * DHEAD)]);
                }
            }
        }
    }
    samp[(size_t)g * DHEAD + d] = __float2bfloat16(acc);
}

// one wave (64 lanes) per row of 256; block = 4 rows
__global__ void ln_kernel(const float* __restrict__ in, float* __restrict__ out,
                          const float* __restrict__ gam, const float* __restrict__ bet)
{
    const int row = blockIdx.x * 4 + (threadIdx.x >> 6);
    const int lane = threadIdx.x & 63;
    float vals[4];
#pragma unroll
    for (int i = 0; i < 4; ++i)
        vals[i] = in[(size_t)row * 256 + i * 64 + lane];
    float s  = vals[0] + vals[1] + vals[2] + vals[3];
    float sq = vals[0] * vals[0] + vals[1] * vals[1] + vals[2] * vals[2] + vals[3] * vals[3];
#pragma unroll
    for (int o = 32; o > 0; o >>= 1) {
        s  += __shfl_xor(s, o);
        sq += __shfl_xor(sq, o);
    }
    float mean = s * (1.f / 256.f);
    float var  = sq * (1.f / 256.f) - mean * mean;
    float rstd = rsqrtf(fmaxf(var, 0.f) + 1e-5f);
#pragma unroll
    for (int i = 0; i < 4; ++i) {
        int c = i * 64 + lane;
        out[(size_t)row * 256 + c] = (vals[i] - mean) * rstd * gam[c] + bet[c];
    }
}

extern "C" void kernel_launch(void* const* d_in, const int* in_sizes, int n_in,
                              void* d_out, int out_size, void* d_ws, size_t ws_size,
                              hipStream_t stream)
{
    const float* src     = (const float*)d_in[0];
    const float* pos     = (const float*)d_in[1];
    const float* ref     = (const float*)d_in[2];
    const float* W_off   = (const float*)d_in[5];
    const float* b_off   = (const float*)d_in[6];
    const float* W_attn  = (const float*)d_in[7];
    const float* b_attn  = (const float*)d_in[8];
    const float* W_val   = (const float*)d_in[9];
    const float* b_val   = (const float*)d_in[10];
    const float* W_out   = (const float*)d_in[11];
    const float* b_out   = (const float*)d_in[12];
    const float* ln_sa_g = (const float*)d_in[13];
    const float* ln_sa_b = (const float*)d_in[14];
    const float* W1      = (const float*)d_in[15];
    const float* b1      = (const float*)d_in[16];
    const float* W2      = (const float*)d_in[17];
    const float* b2      = (const float*)d_in[18];
    const float* ln_ff_g = (const float*)d_in[19];
    const float* ln_ff_b = (const float*)d_in[20];

    char* ws = (char*)d_ws;
    // ws layout (bytes), peak 163,356,672:
    //   [0,          54452224)  off f32  -> later sa_pre f32 -> later hbuf (part)
    //   [54452224,   81678336)  vbuf bf16 -> later hbuf (part)
    //   [81678336,  108904448)  samp bf16 -> later hbuf (part)
    //   [108904448, 163356672)  xbuf f32
    // aw f32 (27.2MB) lives in d_out (dead before d_out's real write in step 9)
    float* off    = (float*)(ws);
    bf16*  vbuf   = (bf16*) (ws + 54452224);
    bf16*  samp   = (bf16*) (ws + 81678336);
    float* xbuf   = (float*)(ws + 108904448);
    float* sa_pre = off;
    bf16*  hbuf   = (bf16*)ws;              // 108,904,448 bytes: [0, 108904448)
    float* aw     = (float*)d_out;          // 27,226,112 bytes scratch
    float* outf   = (float*)d_out;

    dim3 blk(256);
    const int MT = (ROWS + 63) / 64;  // 831

    // 1. v = src @ W_val + b_val -> bf16
    gemm_kernel<float, false, false, false, bf16><<<dim3(4, MT), blk, 0, stream>>>(
        src, nullptr, W_val, b_val, nullptr, vbuf, ROWS, 256, 256);
    // 2. off = (src+pos) @ W_off + b_off -> f32
    gemm_kernel<float, true, false, false, float><<<dim3(4, MT), blk, 0, stream>>>(
        src, pos, W_off, b_off, nullptr, off, ROWS, 256, 256);
    // 3. attn logits = (src+pos) @ W_attn + b_attn -> f32 (in d_out scratch)
    gemm_kernel<float, true, false, false, float><<<dim3(2, MT), blk, 0, stream>>>(
        src, pos, W_attn, b_attn, nullptr, aw, ROWS, 128, 256);
    // 4. softmax over 16 per (b,q,h)
    softmax16_kernel<<<dim3((ROWS * NHEAD + 255) / 256), blk, 0, stream>>>(aw, ROWS * NHEAD);
    // 5. deformable sampling -> samp bf16 [rows, 256] head-major
    sample_kernel<<<dim3(ROWS), blk, 0, stream>>>(vbuf, off, aw, ref, samp);
    // 6. sa_pre = samp @ W_out + b_out + src -> f32 (reuses off region)
    gemm_kernel<bf16, false, false, true, float><<<dim3(4, MT), blk, 0, stream>>>(
        samp, nullptr, W_out, b_out, src, sa_pre, ROWS, 256, 256);
    // 7. x = LN(sa_pre) -> f32
    ln_kernel<<<dim3(ROWS / 4), blk, 0, stream>>>(sa_pre, xbuf, ln_sa_g, ln_sa_b);
    // 8. h = relu(x @ W1 + b1) -> bf16 (reuses [off|vbuf|samp])
    gemm_kernel<float, false, true, false, bf16><<<dim3(16, MT), blk, 0, stream>>>(
        xbuf, nullptr, W1, b1, nullptr, hbuf, ROWS, 1024, 256);
    // 9. y + x = h @ W2 + b2 + x -> f32 into d_out
    gemm_kernel<bf16, false, false, true, float><<<dim3(4, MT), blk, 0, stream>>>(
        hbuf, nullptr, W2, b2, xbuf, outf, ROWS, 256, 1024);
    // 10. final LN in-place on d_out
    ln_kernel<<<dim3(ROWS / 4), blk, 0, stream>>>(outf, outf, ln_ff_g, ln_ff_b);
}

// Round 3
// 578.928 us; speedup vs baseline: 3.6376x; 3.6376x over previous
//
#include <hip/hip_runtime.h>
#include <hip/hip_bf16.h>

typedef __hip_bfloat16 bf16;
typedef short bf16x8 __attribute__((ext_vector_type(8)));
typedef float f32x4  __attribute__((ext_vector_type(4)));

#define ROWS 53176    // B * L_TOTAL
#define LTOT 13294
#define MTILES 416    // ceil(ROWS/128); padded rows read in-bounds garbage

__device__ __forceinline__ float b2f(bf16 v) { return __bfloat162float(v); }

__device__ __forceinline__ void gl2lds16(const void* g, void* l) {
    __builtin_amdgcn_global_load_lds(
        (const __attribute__((address_space(1))) unsigned*)g,
        (__attribute__((address_space(3))) unsigned*)l, 16, 0, 0);
}

// ---------------- MFMA GEMM: C[M,N] = A[M,K](bf16) @ Bt[N,K]^T(bf16) + bias ----------------
// RES: 0 none, 1 f32 residual, 2 bf16 residual. OT: float or bf16.
template<int RES, bool RELU, typename OT>
__global__ __launch_bounds__(256)
void mfma_gemm(const bf16* __restrict__ A, const bf16* __restrict__ Bt,
               const float* __restrict__ bias, const void* __restrict__ res,
               OT* __restrict__ C, int M, int N, int K)
{
    __shared__ __align__(16) short As[128 * 32];
    __shared__ __align__(16) short Bs[128 * 32];
    const int tid  = threadIdx.x;
    const int wave = tid >> 6, lane = tid & 63;
    const int m0 = blockIdx.y * 128, n0 = blockIdx.x * 128;
    const int lrow = lane >> 2, lcol = lane & 3;

    f32x4 acc[4][4];
#pragma unroll
    for (int i = 0; i < 4; ++i)
#pragma unroll
        for (int j = 0; j < 4; ++j) acc[i][j] = (f32x4){0.f, 0.f, 0.f, 0.f};

    const int wrow = (wave >> 1) * 64, wcol = (wave & 1) * 64;
    const int foff = (lane & 15) * 32 + (lane >> 4) * 8;   // fragment LDS offset (shorts)

    for (int kk = 0; kk < K; kk += 32) {
#pragma unroll
        for (int q = 0; q < 2; ++q) {
            int rbase = wave * 32 + q * 16;
            int row = rbase + lrow;
            gl2lds16(A  + (size_t)(m0 + row) * K + kk + lcol * 8, &As[rbase * 32]);
            gl2lds16(Bt + (size_t)(n0 + row) * K + kk + lcol * 8, &Bs[rbase * 32]);
        }
        __syncthreads();
        bf16x8 af[4], bfr[4];
#pragma unroll
        for (int i = 0; i < 4; ++i)
            af[i] = *(const bf16x8*)&As[(wrow + i * 16) * 32 + foff];
#pragma unroll
        for (int j = 0; j < 4; ++j)
            bfr[j] = *(const bf16x8*)&Bs[(wcol + j * 16) * 32 + foff];
#pragma unroll
        for (int i = 0; i < 4; ++i)
#pragma unroll
            for (int j = 0; j < 4; ++j)
                acc[i][j] = __builtin_amdgcn_mfma_f32_16x16x32_bf16(af[i], bfr[j], acc[i][j], 0, 0, 0);
        __syncthreads();
    }

#pragma unroll
    for (int i = 0; i < 4; ++i) {
#pragma unroll
        for (int r = 0; r < 4; ++r) {
            int gm = m0 + wrow + i * 16 + (lane >> 4) * 4 + r;
            if (gm >= M) continue;
#pragma unroll
            for (int j = 0; j < 4; ++j) {
                int gn = n0 + wcol + j * 16 + (lane & 15);
                float v = acc[i][j][r] + bias[gn];
                if (RES == 1) v += ((const float*)res)[(size_t)gm * N + gn];
                if (RES == 2) v += b2f(((const bf16*)res)[(size_t)gm * N + gn]);
                if (RELU) v = fmaxf(v, 0.f);
                if constexpr (sizeof(OT) == 2) C[(size_t)gm * N + gn] = __float2bfloat16(v);
                else                           C[(size_t)gm * N + gn] = v;
            }
        }
    }
}

// ---------------- casts ----------------
__global__ void cast_qs_kernel(const float* __restrict__ s, const float* __restrict__ p,
                               bf16* __restrict__ sb, bf16* __restrict__ qb, int n4)
{
    int i = blockIdx.x * 256 + threadIdx.x;
    if (i >= n4) return;
    float4 sv = ((const float4*)s)[i];
    float4 pv = ((const float4*)p)[i];
    union { bf16 h[4]; uint2 u; } a, b;
    a.h[0] = __float2bfloat16(sv.x); a.h[1] = __float2bfloat16(sv.y);
    a.h[2] = __float2bfloat16(sv.z); a.h[3] = __float2bfloat16(sv.w);
    b.h[0] = __float2bfloat16(sv.x + pv.x); b.h[1] = __float2bfloat16(sv.y + pv.y);
    b.h[2] = __float2bfloat16(sv.z + pv.z); b.h[3] = __float2bfloat16(sv.w + pv.w);
    ((uint2*)sb)[i] = a.u;
    ((uint2*)qb)[i] = b.u;
}

// W [K,N] f32 -> Wt [N,K] bf16
__global__ void wt_cast_kernel(const float* __restrict__ W, bf16* __restrict__ Wt, int K, int N)
{
    int e = blockIdx.x * 256 + threadIdx.x;
    if (e >= K * N) return;
    int n = e / K, k = e - n * K;
    Wt[e] = __float2bfloat16(W[(size_t)k * N + n]);
}

// ---------------- softmax over 16 ----------------
__global__ void softmax16_kernel(float* __restrict__ aw, int n)
{
    int i = blockIdx.x * blockDim.x + threadIdx.x;
    if (i >= n) return;
    float* p = aw + (size_t)i * 16;
    float v[16];
    float m = -1e30f;
#pragma unroll
    for (int j = 0; j < 16; ++j) { v[j] = p[j]; m = fmaxf(m, v[j]); }
    float s = 0.f;
#pragma unroll
    for (int j = 0; j < 16; ++j) { v[j] = expf(v[j] - m); s += v[j]; }
    float inv = 1.f / s;
#pragma unroll
    for (int j = 0; j < 16; ++j) p[j] = v[j] * inv;
}

// ---------------- deformable sampling ----------------
// 16-lane group per (b,q,h); lane covers 2 channels. Phase A: lane=point -> LDS tap table.
__global__ __launch_bounds__(256)
void sample_kernel(const bf16* __restrict__ v, const bf16* __restrict__ off,
                   const float* __restrict__ aw, const float* __restrict__ ref,
                   bf16* __restrict__ samp)
{
    __shared__ int2 tab[16][65];   // [group][p*4+t] = {byte_off, weight_bits}; +1 pad
    const int tid = threadIdx.x;
    const int grp = tid >> 4, lane = tid & 15;
    const int gidx = blockIdx.x * 16 + grp;
    const int h = gidx & 7, bq = gidx >> 3, b = bq / LTOT;

    {   // phase A: this lane handles point p = lane
        const int p = lane, l = p >> 2, pp = p & 3;
        const int   W = (l == 0) ? 100 : (l == 1) ? 50 : (l == 2) ? 25 : 13;
        const int   S = (l == 0) ? 0 : (l == 1) ? 10000 : (l == 2) ? 12500 : 13125;
        const float fW = (float)W;
        float rx = ref[(size_t)bq * 8 + l * 2 + 0];
        float ry = ref[(size_t)bq * 8 + l * 2 + 1];
        float ox = b2f(off[(size_t)bq * 256 + h * 32 + l * 8 + pp * 2 + 0]);
        float oy = b2f(off[(size_t)bq * 256 + h * 32 + l * 8 + pp * 2 + 1]);
        float wgt = aw[(size_t)bq * 128 + h * 16 + l * 4 + pp];
        float x = (rx + ox / fW) * fW - 0.5f;
        float y = (ry + oy / fW) * fW - 0.5f;   // H == W at every level
        float x0f = floorf(x), y0f = floorf(y);
        float lx = x - x0f, ly = y - y0f;
        int x0 = (int)x0f, y0 = (int)y0f;
        float tw[4] = {(1.f - lx) * (1.f - ly), lx * (1.f - ly),
                       (1.f - lx) * ly,         lx * ly};
#pragma unroll
        for (int t = 0; t < 4; ++t) {
            int xi = x0 + (t & 1), yi = y0 + (t >> 1);
            bool ok = (xi >= 0) & (xi < W) & (yi >= 0) & (yi < W);
            int  o  = ok ? (S + yi * W + xi) * 512 : 0;     // byte offset: idx * 256 elems * 2B
            float w = ok ? wgt * tw[t] : 0.f;
            tab[grp][p * 4 + t] = make_int2(o, __float_as_int(w));
        }
    }
    __syncthreads();

    const char* vb = (const char*)v + (size_t)b * LTOT * 512 + h * 64 + lane * 4;
    float a0 = 0.f, a1 = 0.f;
#pragma unroll 4
    for (int e = 0; e < 64; ++e) {
        int2 tw = tab[grp][e];
        unsigned u = *(const unsigned*)(vb + tw.x);
        float w = __int_as_float(tw.y);
        a0 += w * __uint_as_float(u << 16);
        a1 += w * __uint_as_float(u & 0xffff0000u);
    }
    union { struct { bf16 a, b; } h2; unsigned u; } r;
    r.h2.a = __float2bfloat16(a0);
    r.h2.b = __float2bfloat16(a1);
    *(unsigned*)((char*)samp + (size_t)gidx * 64 + lane * 4) = r.u;
}

// ---------------- LayerNorm: one wave per row of 256 ----------------
template<typename IT, typename OT>
__global__ void ln_kernel(const IT* __restrict__ in, OT* __restrict__ out,
                          const float* __restrict__ gam, const float* __restrict__ bet)
{
    const int row = blockIdx.x * 4 + (threadIdx.x >> 6);
    const int lane = threadIdx.x & 63;
    float vals[4];
#pragma unroll
    for (int i = 0; i < 4; ++i) {
        size_t idx = (size_t)row * 256 + i * 64 + lane;
        if constexpr (sizeof(IT) == 2) vals[i] = b2f(((const bf16*)in)[idx]);
        else                           vals[i] = ((const float*)in)[idx];
    }
    float s  = vals[0] + vals[1] + vals[2] + vals[3];
    float sq = vals[0]*vals[0] + vals[1]*vals[1] + vals[2]*vals[2] + vals[3]*vals[3];
#pragma unroll
    for (int o = 32; o > 0; o >>= 1) {
        s  += __shfl_xor(s, o);
        sq += __shfl_xor(sq, o);
    }
    float mean = s * (1.f / 256.f);
    float var  = sq * (1.f / 256.f) - mean * mean;
    float rstd = rsqrtf(fmaxf(var, 0.f) + 1e-5f);
#pragma unroll
    for (int i = 0; i < 4; ++i) {
        int c = i * 64 + lane;
        float o = (vals[i] - mean) * rstd * gam[c] + bet[c];
        if constexpr (sizeof(OT) == 2) ((bf16*)out)[(size_t)row * 256 + c] = __float2bfloat16(o);
        else                           ((float*)out)[(size_t)row * 256 + c] = o;
    }
}

extern "C" void kernel_launch(void* const* d_in, const int* in_sizes, int n_in,
                              void* d_out, int out_size, void* d_ws, size_t ws_size,
                              hipStream_t stream)
{
    const float* src     = (const float*)d_in[0];
    const float* pos     = (const float*)d_in[1];
    const float* ref     = (const float*)d_in[2];
    const float* W_off   = (const float*)d_in[5];
    const float* b_off   = (const float*)d_in[6];
    const float* W_attn  = (const float*)d_in[7];
    const float* b_attn  = (const float*)d_in[8];
    const float* W_val   = (const float*)d_in[9];
    const float* b_val   = (const float*)d_in[10];
    const float* W_out   = (const float*)d_in[11];
    const float* b_out   = (const float*)d_in[12];
    const float* ln_sa_g = (const float*)d_in[13];
    const float* ln_sa_b = (const float*)d_in[14];
    const float* W1      = (const float*)d_in[15];
    const float* b1      = (const float*)d_in[16];
    const float* W2      = (const float*)d_in[17];
    const float* b2      = (const float*)d_in[18];
    const float* ln_ff_g = (const float*)d_in[19];
    const float* ln_ff_b = (const float*)d_in[20];

    char* ws = (char*)d_ws;
    // ws regions (27,226,112 B each; lifetimes step-indexed):
    //  R0 [0):           vbuf(1->5) | sa_pre bf16(6->7) | hbuf[0/4](8->9)
    //  R1 [27,226,112):  off bf16(2->5)                 | hbuf[1/4]
    //  R2 [54,452,224):  qb(0->3)  | samp(5->6)         | hbuf[2/4]
    //  R3 [81,678,336):  sb(0->1)                       | hbuf[3/4]
    //  R4 [108,904,448): xb16(7->9)
    //  R5 [136,130,560 .. 137,637,888): Wt tables (persist)
    //  aw f32: d_out[0, 27,226,112) (3->5; d_out rewritten at 9)
    bf16* vbuf   = (bf16*)(ws);
    bf16* sa_pre = (bf16*)(ws);
    bf16* offb   = (bf16*)(ws + 27226112);
    bf16* qb     = (bf16*)(ws + 54452224);
    bf16* samp   = (bf16*)(ws + 54452224);
    bf16* sb     = (bf16*)(ws + 81678336);
    bf16* hbuf   = (bf16*)(ws);
    bf16* xb16   = (bf16*)(ws + 108904448);
    bf16* Wval_t = (bf16*)(ws + 136130560);
    bf16* Woff_t = (bf16*)(ws + 136261632);
    bf16* Watt_t = (bf16*)(ws + 136392704);
    bf16* Wout_t = (bf16*)(ws + 136458240);
    bf16* W1_t   = (bf16*)(ws + 136589312);
    bf16* W2_t   = (bf16*)(ws + 137113600);
    float* aw    = (float*)d_out;
    float* outf  = (float*)d_out;

    dim3 blk(256);

    // 0. casts
    cast_qs_kernel<<<dim3((ROWS * 256 / 4 + 255) / 256), blk, 0, stream>>>(src, pos, sb, qb, ROWS * 256 / 4);
    wt_cast_kernel<<<dim3((256 * 256 + 255) / 256),  blk, 0, stream>>>(W_val,  Wval_t, 256, 256);
    wt_cast_kernel<<<dim3((256 * 256 + 255) / 256),  blk, 0, stream>>>(W_off,  Woff_t, 256, 256);
    wt_cast_kernel<<<dim3((256 * 128 + 255) / 256),  blk, 0, stream>>>(W_attn, Watt_t, 256, 128);
    wt_cast_kernel<<<dim3((256 * 256 + 255) / 256),  blk, 0, stream>>>(W_out,  Wout_t, 256, 256);
    wt_cast_kernel<<<dim3((256 * 1024 + 255) / 256), blk, 0, stream>>>(W1,     W1_t,   256, 1024);
    wt_cast_kernel<<<dim3((1024 * 256 + 255) / 256), blk, 0, stream>>>(W2,     W2_t,   1024, 256);

    // 1. v = src @ W_val + b_val -> vbuf bf16
    mfma_gemm<0, false, bf16><<<dim3(2, MTILES), blk, 0, stream>>>(
        sb, Wval_t, b_val, nullptr, vbuf, ROWS, 256, 256);
    // 2. off = q @ W_off + b_off -> offb bf16
    mfma_gemm<0, false, bf16><<<dim3(2, MTILES), blk, 0, stream>>>(
        qb, Woff_t, b_off, nullptr, offb, ROWS, 256, 256);
    // 3. aw logits = q @ W_attn + b_attn -> f32 (d_out scratch)
    mfma_gemm<0, false, float><<<dim3(1, MTILES), blk, 0, stream>>>(
        qb, Watt_t, b_attn, nullptr, aw, ROWS, 128, 256);
    // 4. softmax
    softmax16_kernel<<<dim3((ROWS * 8 + 255) / 256), blk, 0, stream>>>(aw, ROWS * 8);
    // 5. sampling -> samp bf16
    sample_kernel<<<dim3(ROWS * 8 / 16), blk, 0, stream>>>(vbuf, offb, aw, ref, samp);
    // 6. sa_pre = samp @ W_out + b_out + src -> bf16
    mfma_gemm<1, false, bf16><<<dim3(2, MTILES), blk, 0, stream>>>(
        samp, Wout_t, b_out, src, sa_pre, ROWS, 256, 256);
    // 7. x = LN(sa_pre) -> xb16
    ln_kernel<bf16, bf16><<<dim3(ROWS / 4), blk, 0, stream>>>(sa_pre, xb16, ln_sa_g, ln_sa_b);
    // 8. h = relu(x @ W1 + b1) -> hbuf bf16
    mfma_gemm<0, true, bf16><<<dim3(8, MTILES), blk, 0, stream>>>(
        xb16, W1_t, b1, nullptr, hbuf, ROWS, 1024, 256);
    // 9. y + x = h @ W2 + b2 + x -> f32 d_out
    mfma_gemm<2, false, float><<<dim3(2, MTILES), blk, 0, stream>>>(
        hbuf, W2_t, b2, xb16, outf, ROWS, 256, 1024);
    // 10. final LN in-place
    ln_kernel<float, float><<<dim3(ROWS / 4), blk, 0, stream>>>(outf, outf, ln_ff_g, ln_ff_b);
}

// Round 4
// 510.108 us; speedup vs baseline: 4.1284x; 1.1349x over previous
//
#include <hip/hip_runtime.h>
#include <hip/hip_bf16.h>

typedef __hip_bfloat16 bf16;
typedef short bf16x8 __attribute__((ext_vector_type(8)));
typedef float f32x4  __attribute__((ext_vector_type(4)));

#define ROWS 53176    // B * L_TOTAL
#define LTOT 13294

__device__ __forceinline__ float b2f(bf16 v) { return __bfloat162float(v); }

__device__ __forceinline__ void gl2lds16(const void* g, void* l) {
    __builtin_amdgcn_global_load_lds(
        (const __attribute__((address_space(1))) unsigned*)g,
        (__attribute__((address_space(3))) unsigned*)l, 16, 0, 0);
}

// ============ narrow MFMA GEMM: 128x128 tile, transposed-acc epilogue ============
// C[M,N] = A[M,K] @ Bt[N,K]^T + bias, optional relu, bf16 out
template<bool RELU>
__global__ __launch_bounds__(256)
void mfma_gemm_n(const bf16* __restrict__ A, const bf16* __restrict__ Bt,
                 const float* __restrict__ bias, bf16* __restrict__ C,
                 int M, int N, int K)
{
    __shared__ __align__(16) short As[128 * 32];
    __shared__ __align__(16) short Bs[128 * 32];
    const int tid  = threadIdx.x;
    const int wave = tid >> 6, lane = tid & 63;
    const int m0 = blockIdx.y * 128, n0 = blockIdx.x * 128;
    const int lrow = lane >> 2, lcol = lane & 3;
    const int quad = lane >> 4;

    f32x4 acc[4][4];
#pragma unroll
    for (int i = 0; i < 4; ++i)
#pragma unroll
        for (int j = 0; j < 4; ++j) acc[i][j] = (f32x4){0.f, 0.f, 0.f, 0.f};

    const int wM = (wave >> 1) * 64, wN = (wave & 1) * 64;
    const int foff = (lane & 15) * 32 + quad * 8;

    for (int kk = 0; kk < K; kk += 32) {
#pragma unroll
        for (int q = 0; q < 2; ++q) {
            int rbase = wave * 32 + q * 16;
            int row = rbase + lrow;
            gl2lds16(A  + (size_t)(m0 + row) * K + kk + lcol * 8, &As[rbase * 32]);
            gl2lds16(Bt + (size_t)(n0 + row) * K + kk + lcol * 8, &Bs[rbase * 32]);
        }
        __syncthreads();
        bf16x8 af[4], bfr[4];
#pragma unroll
        for (int i = 0; i < 4; ++i)
            af[i] = *(const bf16x8*)&As[(wM + i * 16) * 32 + foff];
#pragma unroll
        for (int j = 0; j < 4; ++j)
            bfr[j] = *(const bf16x8*)&Bs[(wN + j * 16) * 32 + foff];
        // transposed: D row-space = Bt rows (N), col-space = A rows (M)
#pragma unroll
        for (int i = 0; i < 4; ++i)
#pragma unroll
            for (int j = 0; j < 4; ++j)
                acc[i][j] = __builtin_amdgcn_mfma_f32_16x16x32_bf16(bfr[j], af[i], acc[i][j], 0, 0, 0);
        __syncthreads();
    }

    float4 b4[4];
#pragma unroll
    for (int j = 0; j < 4; ++j)
        b4[j] = *(const float4*)&bias[n0 + wN + j * 16 + quad * 4];

#pragma unroll
    for (int i = 0; i < 4; ++i) {
        int gm = m0 + wM + i * 16 + (lane & 15);
        if (gm >= M) continue;
#pragma unroll
        for (int j = 0; j < 4; ++j) {
            int gn = n0 + wN + j * 16 + quad * 4;
            union { bf16 h[4]; uint2 u2; } pk;
#pragma unroll
            for (int r = 0; r < 4; ++r) {
                float v = acc[i][j][r] + ((const float*)&b4[j])[r];
                if (RELU) v = fmaxf(v, 0.f);
                pk.h[r] = __float2bfloat16(v);
            }
            *(uint2*)&C[(size_t)gm * N + gn] = pk.u2;
        }
    }
}

// ============ wide MFMA GEMM with fused LayerNorm: 128x256 tile, 512 thr ============
// out = LN( A[M,K] @ Bt[256,K]^T + bias + res ) ; res f32 or bf16; out f32 or bf16
template<bool RES_BF16, typename OT>
__global__ __launch_bounds__(512)
void mfma_gemm_ln(const bf16* __restrict__ A, const bf16* __restrict__ Bt,
                  const float* __restrict__ bias, const void* __restrict__ res,
                  OT* __restrict__ C, const float* __restrict__ gam,
                  const float* __restrict__ bet, int M, int K)
{
    __shared__ __align__(16) short As[128 * 32];
    __shared__ __align__(16) short Bs[256 * 32];
    __shared__ float rsum[128], rsq[128];
    const int tid  = threadIdx.x;
    const int wave = tid >> 6, lane = tid & 63;
    const int m0 = blockIdx.x * 128;
    const int lrow = lane >> 2, lcol = lane & 3;
    const int quad = lane >> 4;
    if (tid < 128) { rsum[tid] = 0.f; rsq[tid] = 0.f; }

    f32x4 acc[4][4];
#pragma unroll
    for (int i = 0; i < 4; ++i)
#pragma unroll
        for (int j = 0; j < 4; ++j) acc[i][j] = (f32x4){0.f, 0.f, 0.f, 0.f};

    const int wM = (wave >> 2) * 64, wN = (wave & 3) * 64;
    const int foff = (lane & 15) * 32 + quad * 8;

    for (int kk = 0; kk < K; kk += 32) {
#pragma unroll
        for (int q = 0; q < 3; ++q) {
            int r = wave * 48 + q * 16;
            if (r < 128) {
                gl2lds16(A + (size_t)(m0 + r + lrow) * K + kk + lcol * 8, &As[r * 32]);
            } else {
                int rr = r - 128;
                gl2lds16(Bt + (size_t)(rr + lrow) * K + kk + lcol * 8, &Bs[rr * 32]);
            }
        }
        __syncthreads();
        bf16x8 af[4], bfr[4];
#pragma unroll
        for (int i = 0; i < 4; ++i)
            af[i] = *(const bf16x8*)&As[(wM + i * 16) * 32 + foff];
#pragma unroll
        for (int j = 0; j < 4; ++j)
            bfr[j] = *(const bf16x8*)&Bs[(wN + j * 16) * 32 + foff];
#pragma unroll
        for (int i = 0; i < 4; ++i)
#pragma unroll
            for (int j = 0; j < 4; ++j)
                acc[i][j] = __builtin_amdgcn_mfma_f32_16x16x32_bf16(bfr[j], af[i], acc[i][j], 0, 0, 0);
        __syncthreads();
    }

    float4 b4[4], g4[4], be4[4];
#pragma unroll
    for (int j = 0; j < 4; ++j) {
        int gn = wN + j * 16 + quad * 4;
        b4[j]  = *(const float4*)&bias[gn];
        g4[j]  = *(const float4*)&gam[gn];
        be4[j] = *(const float4*)&bet[gn];
    }

    // bias + residual, accumulate row stats
    float lsum[4], lsq[4];
#pragma unroll
    for (int i = 0; i < 4; ++i) {
        int gm = m0 + wM + i * 16 + (lane & 15);
        lsum[i] = 0.f; lsq[i] = 0.f;
#pragma unroll
        for (int j = 0; j < 4; ++j) {
            int gn = wN + j * 16 + quad * 4;
            float r4[4] = {0.f, 0.f, 0.f, 0.f};
            if (gm < M) {
                if (RES_BF16) {
                    uint2 ru = *(const uint2*)&((const bf16*)res)[(size_t)gm * 256 + gn];
                    const bf16* rh = (const bf16*)&ru;
#pragma unroll
                    for (int r = 0; r < 4; ++r) r4[r] = b2f(rh[r]);
                } else {
                    float4 rf = *(const float4*)&((const float*)res)[(size_t)gm * 256 + gn];
#pragma unroll
                    for (int r = 0; r < 4; ++r) r4[r] = ((const float*)&rf)[r];
                }
            }
#pragma unroll
            for (int r = 0; r < 4; ++r) {
                float v = acc[i][j][r] + ((const float*)&b4[j])[r] + r4[r];
                acc[i][j][r] = v;
                lsum[i] += v;
                lsq[i]  += v * v;
            }
        }
#pragma unroll
        for (int mask = 16; mask <= 32; mask <<= 1) {
            lsum[i] += __shfl_xor(lsum[i], mask);
            lsq[i]  += __shfl_xor(lsq[i], mask);
        }
    }
    if (quad == 0) {
#pragma unroll
        for (int i = 0; i < 4; ++i) {
            atomicAdd(&rsum[wM + i * 16 + (lane & 15)], lsum[i]);
            atomicAdd(&rsq [wM + i * 16 + (lane & 15)], lsq[i]);
        }
    }
    __syncthreads();

#pragma unroll
    for (int i = 0; i < 4; ++i) {
        int lr = wM + i * 16 + (lane & 15);
        int gm = m0 + lr;
        if (gm >= M) continue;
        float mean = rsum[lr] * (1.f / 256.f);
        float var  = rsq[lr] * (1.f / 256.f) - mean * mean;
        float rstd = rsqrtf(fmaxf(var, 0.f) + 1e-5f);
#pragma unroll
        for (int j = 0; j < 4; ++j) {
            int gn = wN + j * 16 + quad * 4;
            if constexpr (sizeof(OT) == 2) {
                union { bf16 h[4]; uint2 u2; } pk;
#pragma unroll
                for (int r = 0; r < 4; ++r)
                    pk.h[r] = __float2bfloat16((acc[i][j][r] - mean) * rstd *
                              ((const float*)&g4[j])[r] + ((const float*)&be4[j])[r]);
                *(uint2*)&((bf16*)C)[(size_t)gm * 256 + gn] = pk.u2;
            } else {
                float4 o;
#pragma unroll
                for (int r = 0; r < 4; ++r)
                    ((float*)&o)[r] = (acc[i][j][r] - mean) * rstd *
                              ((const float*)&g4[j])[r] + ((const float*)&be4[j])[r];
                *(float4*)&((float*)C)[(size_t)gm * 256 + gn] = o;
            }
        }
    }
}

// ============ casts ============
__global__ void cast_qs_kernel(const float* __restrict__ s, const float* __restrict__ p,
                               bf16* __restrict__ sb, bf16* __restrict__ qb, int n4)
{
    int i = blockIdx.x * 256 + threadIdx.x;
    if (i >= n4) return;
    float4 sv = ((const float4*)s)[i];
    float4 pv = ((const float4*)p)[i];
    union { bf16 h[4]; uint2 u; } a, b;
    a.h[0] = __float2bfloat16(sv.x); a.h[1] = __float2bfloat16(sv.y);
    a.h[2] = __float2bfloat16(sv.z); a.h[3] = __float2bfloat16(sv.w);
    b.h[0] = __float2bfloat16(sv.x + pv.x); b.h[1] = __float2bfloat16(sv.y + pv.y);
    b.h[2] = __float2bfloat16(sv.z + pv.z); b.h[3] = __float2bfloat16(sv.w + pv.w);
    ((uint2*)sb)[i] = a.u;
    ((uint2*)qb)[i] = b.u;
}

// W [K,N] f32 -> Wt [N,K] bf16
__global__ void wt_cast_kernel(const float* __restrict__ W, bf16* __restrict__ Wt, int K, int N)
{
    int e = blockIdx.x * 256 + threadIdx.x;
    if (e >= K * N) return;
    int n = e / K, k = e - n * K;
    Wt[e] = __float2bfloat16(W[(size_t)k * N + n]);
}

// concat W_off(256x256) | W_attn(256x128) -> Wcat_t[384][256] bf16, bcat[384] f32
__global__ void wcat_cast_kernel(const float* __restrict__ Woff, const float* __restrict__ Wattn,
                                 const float* __restrict__ boff, const float* __restrict__ battn,
                                 bf16* __restrict__ Wt, float* __restrict__ bcat)
{
    int e = blockIdx.x * 256 + threadIdx.x;
    if (e < 384) bcat[e] = (e < 256) ? boff[e] : battn[e - 256];
    if (e >= 384 * 256) return;
    int n = e >> 8, k = e & 255;
    float w = (n < 256) ? Woff[(size_t)k * 256 + n] : Wattn[(size_t)k * 128 + (n - 256)];
    Wt[e] = __float2bfloat16(w);
}

// ============ deformable sampling + fused softmax ============
// 16-lane group per (b,q,h); lane covers 2 channels; phase A: lane = point.
__global__ __launch_bounds__(256)
void sample_kernel(const bf16* __restrict__ v, const bf16* __restrict__ ocat,
                   const float* __restrict__ ref, bf16* __restrict__ samp)
{
    __shared__ int4 tab[16][33];   // [group][p*2 + pair]: {off0,w0,off1,w1}
    const int tid = threadIdx.x;
    const int grp = tid >> 4, lane = tid & 15;
    const int gidx = blockIdx.x * 16 + grp;
    const int h = gidx & 7, bq = gidx >> 3, b = bq / LTOT;

    {   // phase A: point p = lane
        const int p = lane, l = p >> 2, pp = p & 3;
        const int W = (l == 0) ? 100 : (l == 1) ? 50 : (l == 2) ? 25 : 13;
        const int S = (l == 0) ? 0 : (l == 1) ? 10000 : (l == 2) ? 12500 : 13125;
        const float fW = (float)W;
        float rx = ref[(size_t)bq * 8 + l * 2 + 0];
        float ry = ref[(size_t)bq * 8 + l * 2 + 1];
        const bf16* ob = ocat + (size_t)bq * 384;
        float ox = b2f(ob[h * 32 + l * 8 + pp * 2 + 0]);
        float oy = b2f(ob[h * 32 + l * 8 + pp * 2 + 1]);
        float lg = b2f(ob[256 + h * 16 + p]);
        // softmax over the 16 lanes of this group
        float m = lg;
#pragma unroll
        for (int mask = 1; mask <= 8; mask <<= 1) m = fmaxf(m, __shfl_xor(m, mask));
        float ev = __expf(lg - m);
        float s = ev;
#pragma unroll
        for (int mask = 1; mask <= 8; mask <<= 1) s += __shfl_xor(s, mask);
        float wgt = ev / s;

        float x = (rx + ox / fW) * fW - 0.5f;
        float y = (ry + oy / fW) * fW - 0.5f;   // H == W at every level
        float x0f = floorf(x), y0f = floorf(y);
        float lx = x - x0f, ly = y - y0f;
        int x0 = (int)x0f, y0 = (int)y0f;
        float tw[4] = {(1.f - lx) * (1.f - ly), lx * (1.f - ly),
                       (1.f - lx) * ly,         lx * ly};
        const int base = (b * LTOT + S) * 512 + h * 64;   // byte offset in v
        int  o[4]; float w[4];
#pragma unroll
        for (int t = 0; t < 4; ++t) {
            int xi = x0 + (t & 1), yi = y0 + (t >> 1);
            bool ok = (xi >= 0) & (xi < W) & (yi >= 0) & (yi < W);
            o[t] = ok ? base + (yi * W + xi) * 512 : 0;
            w[t] = ok ? wgt * tw[t] : 0.f;
        }
        tab[grp][p * 2 + 0] = make_int4(o[0], __float_as_int(w[0]), o[1], __float_as_int(w[1]));
        tab[grp][p * 2 + 1] = make_int4(o[2], __float_as_int(w[2]), o[3], __float_as_int(w[3]));
    }
    __syncthreads();

    const int lofs = lane * 4;
    const char* vc = (const char*)v;
    float a0 = 0.f, a1 = 0.f;
#pragma unroll 4
    for (int e2 = 0; e2 < 32; ++e2) {
        int4 q = tab[grp][e2];
        unsigned u0 = *(const unsigned*)(vc + (size_t)(unsigned)(q.x + lofs));
        unsigned u1 = *(const unsigned*)(vc + (size_t)(unsigned)(q.z + lofs));
        float w0 = __int_as_float(q.y), w1 = __int_as_float(q.w);
        a0 += w0 * __uint_as_float(u0 << 16);
        a1 += w0 * __uint_as_float(u0 & 0xffff0000u);
        a0 += w1 * __uint_as_float(u1 << 16);
        a1 += w1 * __uint_as_float(u1 & 0xffff0000u);
    }
    union { struct { bf16 a, b; } h2; unsigned u; } r;
    r.h2.a = __float2bfloat16(a0);
    r.h2.b = __float2bfloat16(a1);
    *(unsigned*)((char*)samp + (size_t)gidx * 64 + lane * 4) = r.u;
}

extern "C" void kernel_launch(void* const* d_in, const int* in_sizes, int n_in,
                              void* d_out, int out_size, void* d_ws, size_t ws_size,
                              hipStream_t stream)
{
    const float* src     = (const float*)d_in[0];
    const float* pos     = (const float*)d_in[1];
    const float* ref     = (const float*)d_in[2];
    const float* W_off   = (const float*)d_in[5];
    const float* b_off   = (const float*)d_in[6];
    const float* W_attn  = (const float*)d_in[7];
    const float* b_attn  = (const float*)d_in[8];
    const float* W_val   = (const float*)d_in[9];
    const float* b_val   = (const float*)d_in[10];
    const float* W_out   = (const float*)d_in[11];
    const float* b_out   = (const float*)d_in[12];
    const float* ln_sa_g = (const float*)d_in[13];
    const float* ln_sa_b = (const float*)d_in[14];
    const float* W1      = (const float*)d_in[15];
    const float* b1      = (const float*)d_in[16];
    const float* W2      = (const float*)d_in[17];
    const float* b2      = (const float*)d_in[18];
    const float* ln_ff_g = (const float*)d_in[19];
    const float* ln_ff_b = (const float*)d_in[20];

    char* ws = (char*)d_ws;
    // ws layout (bytes):
    //   sb   [0, 27226112)               cast->G1;  then samp (sample->G6)
    //   qb   [27226112, 54452224)        cast->G23
    //   vbuf [54452224, 81678336)        G1->sample
    //   ocat [81678336, 122517504)       G23->sample  (ROWS*384*2)
    //   xb16 [122517504, 149743616)      G6->G9
    //   wts  [149743616, 151252480)
    //   hbuf [0, 108904448)              G8->G9 (overlaps sb/qb/vbuf/ocat-head, all dead)
    bf16* sb     = (bf16*)(ws);
    bf16* samp   = (bf16*)(ws);
    bf16* qb     = (bf16*)(ws + 27226112);
    bf16* vbuf   = (bf16*)(ws + 54452224);
    bf16* ocat   = (bf16*)(ws + 81678336);
    bf16* xb16   = (bf16*)(ws + 122517504);
    bf16* hbuf   = (bf16*)(ws);
    bf16* Wval_t = (bf16*)(ws + 149743616);
    bf16* Wcat_t = (bf16*)(ws + 149874688);
    float* bcat  = (float*)(ws + 150071296);
    bf16* Wout_t = (bf16*)(ws + 150072832);
    bf16* W1_t   = (bf16*)(ws + 150203904);
    bf16* W2_t   = (bf16*)(ws + 150728192);
    float* outf  = (float*)d_out;

    dim3 blk(256);

    // 0. casts
    cast_qs_kernel<<<dim3((ROWS * 64 + 255) / 256), blk, 0, stream>>>(src, pos, sb, qb, ROWS * 64);
    wt_cast_kernel<<<dim3((256 * 256 + 255) / 256),  blk, 0, stream>>>(W_val, Wval_t, 256, 256);
    wcat_cast_kernel<<<dim3((384 * 256 + 255) / 256), blk, 0, stream>>>(W_off, W_attn, b_off, b_attn, Wcat_t, bcat);
    wt_cast_kernel<<<dim3((256 * 256 + 255) / 256),  blk, 0, stream>>>(W_out, Wout_t, 256, 256);
    wt_cast_kernel<<<dim3((256 * 1024 + 255) / 256), blk, 0, stream>>>(W1, W1_t, 256, 1024);
    wt_cast_kernel<<<dim3((1024 * 256 + 255) / 256), blk, 0, stream>>>(W2, W2_t, 1024, 256);

    // 1. v = src @ W_val + b_val -> vbuf bf16
    mfma_gemm_n<false><<<dim3(2, 416), blk, 0, stream>>>(sb, Wval_t, b_val, vbuf, ROWS, 256, 256);
    // 2+3. [off | attn logits] = q @ Wcat + bcat -> ocat bf16 [ROWS][384]
    mfma_gemm_n<false><<<dim3(3, 416), blk, 0, stream>>>(qb, Wcat_t, bcat, ocat, ROWS, 384, 256);
    // 4+5. softmax (fused) + sampling -> samp bf16
    sample_kernel<<<dim3(ROWS * 8 / 16), blk, 0, stream>>>(vbuf, ocat, ref, samp);
    // 6+7. x = LN(samp @ W_out + b_out + src) -> xb16
    mfma_gemm_ln<false, bf16><<<dim3(416), dim3(512), 0, stream>>>(
        samp, Wout_t, b_out, src, xb16, ln_sa_g, ln_sa_b, ROWS, 256);
    // 8. h = relu(x @ W1 + b1) -> hbuf bf16
    mfma_gemm_n<true><<<dim3(8, 416), blk, 0, stream>>>(xb16, W1_t, b1, hbuf, ROWS, 1024, 256);
    // 9+10. out = LN(h @ W2 + b2 + x) -> f32 d_out
    mfma_gemm_ln<true, float><<<dim3(416), dim3(512), 0, stream>>>(
        hbuf, W2_t, b2, xb16, outf, ln_ff_g, ln_ff_b, ROWS, 1024);
}